// Round 1
// baseline (840.472 us; speedup 1.0000x reference)
//
#include <hip/hip_runtime.h>

#define FEAT 64
#define HDIM 128
#define BN_EPS 1e-5f

// ---------------- K0: zero stats + deg + agg ----------------
__global__ void k0_zero(float* __restrict__ ws, int N, int aggOff) {
    int stride = gridDim.x * blockDim.x;
    int gid = blockIdx.x * blockDim.x + threadIdx.x;
    // stats (256) + deg (N)
    for (int i = gid; i < 256 + N; i += stride) ws[i] = 0.0f;
    // agg region, float4
    float4* a4 = (float4*)(ws + aggOff);
    int n4 = N * (FEAT / 4);
    float4 z = make_float4(0.f, 0.f, 0.f, 0.f);
    for (int i = gid; i < n4; i += stride) a4[i] = z;
}

// ---------------- K1: column sums / sumsq ----------------
__global__ __launch_bounds__(256) void k1_stats(const float* __restrict__ x,
                                                float* __restrict__ ws, int N) {
    int col = threadIdx.x & 63;
    int rowInBlk = threadIdx.x >> 6;  // 0..3
    float s = 0.f, sq = 0.f;
    for (int r = blockIdx.x * 4 + rowInBlk; r < N; r += gridDim.x * 4) {
        float v = x[(size_t)r * FEAT + col];
        s += v;
        sq += v * v;
    }
    __shared__ float sd[256];
    __shared__ float sd2[256];
    sd[threadIdx.x] = s;
    sd2[threadIdx.x] = sq;
    __syncthreads();
    if (threadIdx.x < 64) {
        s = sd[col] + sd[col + 64] + sd[col + 128] + sd[col + 192];
        sq = sd2[col] + sd2[col + 64] + sd2[col + 128] + sd2[col + 192];
        atomicAdd(&ws[col], s);
        atomicAdd(&ws[64 + col], sq);
    }
}

// ---------------- K2: finalize scale/shift ----------------
__global__ void k2_finalize(float* __restrict__ ws, const float* __restrict__ gamma,
                            const float* __restrict__ beta, int N) {
    int c = threadIdx.x;  // 64 threads
    float invN = 1.0f / (float)N;
    float mean = ws[c] * invN;
    float var = ws[64 + c] * invN - mean * mean;
    float sc = rsqrtf(var + BN_EPS) * gamma[c];
    ws[128 + c] = sc;
    ws[192 + c] = beta[c] - mean * sc;
}

// ---------------- K3: xn = x*scale + shift ----------------
__global__ __launch_bounds__(256) void k3_norm(const float* __restrict__ x,
                                               const float* __restrict__ ws,
                                               float* __restrict__ xn, int N) {
    const float4* x4 = (const float4*)x;
    float4* o4 = (float4*)xn;
    int n4 = N * (FEAT / 4);
    int stride = gridDim.x * blockDim.x;
    for (int i = blockIdx.x * blockDim.x + threadIdx.x; i < n4; i += stride) {
        int cg = (i & 15) << 2;  // starting column of this float4
        float4 v = x4[i];
        float4 sc = *(const float4*)(ws + 128 + cg);
        float4 sh = *(const float4*)(ws + 192 + cg);
        v.x = v.x * sc.x + sh.x;
        v.y = v.y * sc.y + sh.y;
        v.z = v.z * sc.z + sh.z;
        v.w = v.w * sc.w + sh.w;
        o4[i] = v;
    }
}

// ---------------- K4: edge scatter (atomic) ----------------
// one thread per (edge, feature); 4 edges per 256-thread block
__global__ __launch_bounds__(256) void k4_scatter(const int* __restrict__ ei,
                                                  const float* __restrict__ xn,
                                                  float* __restrict__ agg,
                                                  float* __restrict__ deg, int E) {
    int gid = blockIdx.x * 256 + threadIdx.x;
    int e = gid >> 6;
    if (e >= E) return;
    int f = gid & 63;
    int src = ei[e];
    int dst = ei[E + e];
    float v = xn[(size_t)src * FEAT + f];
    atomicAdd(&agg[(size_t)dst * FEAT + f], v);
    if (f == 0) atomicAdd(&deg[dst], 1.0f);
}

// ---------------- K5: fused GEMM + classifier head ----------------
// one thread per row; row data in registers; weight reads are loop-uniform
__global__ __launch_bounds__(256) void k5_gemm(const float* __restrict__ agg,
                                               const float* __restrict__ xn,
                                               const float* __restrict__ deg,
                                               const float* __restrict__ Wl,
                                               const float* __restrict__ bl,
                                               const float* __restrict__ Wr,
                                               const float* __restrict__ W1,
                                               const float* __restrict__ b1,
                                               const float* __restrict__ W2,
                                               const float* __restrict__ b2,
                                               float* __restrict__ out, int N) {
    int i = blockIdx.x * 256 + threadIdx.x;
    if (i >= N) return;
    float a[FEAT], xr[FEAT];
    float dinv = 1.0f / fmaxf(deg[i], 1.0f);
    const float4* ap = (const float4*)(agg + (size_t)i * FEAT);
    const float4* xp = (const float4*)(xn + (size_t)i * FEAT);
#pragma unroll
    for (int k = 0; k < FEAT / 4; k++) {
        float4 av = ap[k];
        a[4 * k + 0] = av.x * dinv;
        a[4 * k + 1] = av.y * dinv;
        a[4 * k + 2] = av.z * dinv;
        a[4 * k + 3] = av.w * dinv;
        float4 xv = xp[k];
        xr[4 * k + 0] = xv.x;
        xr[4 * k + 1] = xv.y;
        xr[4 * k + 2] = xv.z;
        xr[4 * k + 3] = xv.w;
    }
    float t[16];
#pragma unroll
    for (int m = 0; m < 16; m++) t[m] = b1[m];
    for (int j = 0; j < HDIM; j++) {
        float h = bl[j];
#pragma unroll
        for (int k = 0; k < FEAT; k++) {
            h += a[k] * Wl[k * HDIM + j] + xr[k] * Wr[k * HDIM + j];
        }
        h = fmaxf(h, 0.0f);
#pragma unroll
        for (int m = 0; m < 16; m++) t[m] += h * W1[j * 16 + m];
    }
    float o0 = b2[0], o1 = b2[1];
#pragma unroll
    for (int m = 0; m < 16; m++) {
        float tm = fmaxf(t[m], 0.0f);
        o0 += tm * W2[m * 2 + 0];
        o1 += tm * W2[m * 2 + 1];
    }
    out[(size_t)i * 2 + 0] = o0;
    out[(size_t)i * 2 + 1] = o1;
}

extern "C" void kernel_launch(void* const* d_in, const int* in_sizes, int n_in,
                              void* d_out, int out_size, void* d_ws, size_t ws_size,
                              hipStream_t stream) {
    const float* x = (const float*)d_in[0];
    const int* ei = (const int*)d_in[1];
    // d_in[2] edge_weight, d_in[3] edge_features, d_in[4] adj, d_in[5] T: unused
    const float* gamma = (const float*)d_in[6];
    const float* beta = (const float*)d_in[7];
    const float* Wl = (const float*)d_in[8];
    const float* bl = (const float*)d_in[9];
    const float* Wr = (const float*)d_in[10];
    const float* W1 = (const float*)d_in[11];
    const float* b1 = (const float*)d_in[12];
    const float* W2 = (const float*)d_in[13];
    const float* b2 = (const float*)d_in[14];

    int N = in_sizes[0] / FEAT;
    int E = in_sizes[1] / 2;

    float* ws = (float*)d_ws;
    int degOff = 256;
    int xnOff = (256 + N + 3) & ~3;       // float4-aligned
    int aggOff = xnOff + N * FEAT;        // float4-aligned (N*64 % 4 == 0)

    float* out = (float*)d_out;

    hipLaunchKernelGGL(k0_zero, dim3(2048), dim3(256), 0, stream, ws, N, aggOff);
    hipLaunchKernelGGL(k1_stats, dim3(1024), dim3(256), 0, stream, x, ws, N);
    hipLaunchKernelGGL(k2_finalize, dim3(1), dim3(64), 0, stream, ws, gamma, beta, N);
    hipLaunchKernelGGL(k3_norm, dim3(2048), dim3(256), 0, stream, x, ws, ws + xnOff, N);

    int nscatter = E * FEAT;
    hipLaunchKernelGGL(k4_scatter, dim3((nscatter + 255) / 256), dim3(256), 0, stream,
                       ei, ws + xnOff, ws + aggOff, ws + degOff, E);

    hipLaunchKernelGGL(k5_gemm, dim3((N + 255) / 256), dim3(256), 0, stream,
                       ws + aggOff, ws + xnOff, ws + degOff,
                       Wl, bl, Wr, W1, b1, W2, b2, out, N);
}

// Round 2
// 732.558 us; speedup vs baseline: 1.1473x; 1.1473x over previous
//
#include <hip/hip_runtime.h>

#define FEAT 64
#define HDIM 128
#define BN_EPS 1e-5f

// ---------------- K0: zero stats + deg + agg ----------------
__global__ void k0_zero(float* __restrict__ ws, int N, int aggOff) {
    int stride = gridDim.x * blockDim.x;
    int gid = blockIdx.x * blockDim.x + threadIdx.x;
    // stats (256) + deg (N)
    for (int i = gid; i < 256 + N; i += stride) ws[i] = 0.0f;
    // agg region, float4
    float4* a4 = (float4*)(ws + aggOff);
    int n4 = N * (FEAT / 4);
    float4 z = make_float4(0.f, 0.f, 0.f, 0.f);
    for (int i = gid; i < n4; i += stride) a4[i] = z;
}

// ---------------- K1: column sums / sumsq ----------------
__global__ __launch_bounds__(256) void k1_stats(const float* __restrict__ x,
                                                float* __restrict__ ws, int N) {
    int col = threadIdx.x & 63;
    int rowInBlk = threadIdx.x >> 6;  // 0..3
    float s = 0.f, sq = 0.f;
    for (int r = blockIdx.x * 4 + rowInBlk; r < N; r += gridDim.x * 4) {
        float v = x[(size_t)r * FEAT + col];
        s += v;
        sq += v * v;
    }
    __shared__ float sd[256];
    __shared__ float sd2[256];
    sd[threadIdx.x] = s;
    sd2[threadIdx.x] = sq;
    __syncthreads();
    if (threadIdx.x < 64) {
        s = sd[col] + sd[col + 64] + sd[col + 128] + sd[col + 192];
        sq = sd2[col] + sd2[col + 64] + sd2[col + 128] + sd2[col + 192];
        atomicAdd(&ws[col], s);
        atomicAdd(&ws[64 + col], sq);
    }
}

// ---------------- K2: finalize scale/shift ----------------
__global__ void k2_finalize(float* __restrict__ ws, const float* __restrict__ gamma,
                            const float* __restrict__ beta, int N) {
    int c = threadIdx.x;  // 64 threads
    float invN = 1.0f / (float)N;
    float mean = ws[c] * invN;
    float var = ws[64 + c] * invN - mean * mean;
    float sc = rsqrtf(var + BN_EPS) * gamma[c];
    ws[128 + c] = sc;
    ws[192 + c] = beta[c] - mean * sc;
}

// ---------------- K3: xn = x*scale + shift ----------------
__global__ __launch_bounds__(256) void k3_norm(const float* __restrict__ x,
                                               const float* __restrict__ ws,
                                               float* __restrict__ xn, int N) {
    const float4* x4 = (const float4*)x;
    float4* o4 = (float4*)xn;
    int n4 = N * (FEAT / 4);
    int stride = gridDim.x * blockDim.x;
    for (int i = blockIdx.x * blockDim.x + threadIdx.x; i < n4; i += stride) {
        int cg = (i & 15) << 2;  // starting column of this float4
        float4 v = x4[i];
        float4 sc = *(const float4*)(ws + 128 + cg);
        float4 sh = *(const float4*)(ws + 192 + cg);
        v.x = v.x * sc.x + sh.x;
        v.y = v.y * sc.y + sh.y;
        v.z = v.z * sc.z + sh.z;
        v.w = v.w * sc.w + sh.w;
        o4[i] = v;
    }
}

// ---------------- K4: edge scatter (atomic) ----------------
// one thread per (edge, feature); 4 edges per 256-thread block
__global__ __launch_bounds__(256) void k4_scatter(const int* __restrict__ ei,
                                                  const float* __restrict__ xn,
                                                  float* __restrict__ agg,
                                                  float* __restrict__ deg, int E) {
    int gid = blockIdx.x * 256 + threadIdx.x;
    int e = gid >> 6;
    if (e >= E) return;
    int f = gid & 63;
    int src = ei[e];
    int dst = ei[E + e];
    float v = xn[(size_t)src * FEAT + f];
    atomicAdd(&agg[(size_t)dst * FEAT + f], v);
    if (f == 0) atomicAdd(&deg[dst], 1.0f);
}

// ---------------- K5: block-tiled fused GEMM + classifier head ----------------
// 256 threads = 64 rows x 4 j-groups of 32 columns. Row data staged in LDS
// (pad 65 -> 2-way bank alias = free). Weights read wave-uniform (L1 broadcast).
// Per-thread: 32 h accumulators in VGPRs -> no spill.
#define ROWS 64
#define LDP 65  // padded LDS row stride

__global__ __launch_bounds__(256) void k5_gemm(const float* __restrict__ agg,
                                               const float* __restrict__ xn,
                                               const float* __restrict__ deg,
                                               const float* __restrict__ Wl,
                                               const float* __restrict__ bl,
                                               const float* __restrict__ Wr,
                                               const float* __restrict__ W1,
                                               const float* __restrict__ b1,
                                               const float* __restrict__ W2,
                                               const float* __restrict__ b2,
                                               float* __restrict__ out, int N) {
    __shared__ float smem[2 * ROWS * LDP];  // a_s, x_s; reused for t-partials
    float* a_s = smem;
    float* x_s = smem + ROWS * LDP;

    int row0 = blockIdx.x * ROWS;
    int t = threadIdx.x;

    // ---- stage 64 rows of agg (scaled by 1/deg) and xn into LDS ----
    for (int i = t; i < ROWS * 16; i += 256) {
        int r = i >> 4, cg = i & 15;
        int row = row0 + r;
        float4 av = make_float4(0.f, 0.f, 0.f, 0.f);
        float4 xv = av;
        float dinv = 0.f;
        if (row < N) {
            av = ((const float4*)(agg + (size_t)row * FEAT))[cg];
            xv = ((const float4*)(xn + (size_t)row * FEAT))[cg];
            dinv = 1.0f / fmaxf(deg[row], 1.0f);
        }
        int base = r * LDP + cg * 4;
        a_s[base + 0] = av.x * dinv;
        a_s[base + 1] = av.y * dinv;
        a_s[base + 2] = av.z * dinv;
        a_s[base + 3] = av.w * dinv;
        x_s[base + 0] = xv.x;
        x_s[base + 1] = xv.y;
        x_s[base + 2] = xv.z;
        x_s[base + 3] = xv.w;
    }
    __syncthreads();

    int row = t & 63;
    int jg = t >> 6;  // 0..3; wave-uniform (wave=64)
    int j0 = jg * 32;

    float h[32];
#pragma unroll
    for (int jj = 0; jj < 32; jj++) h[jj] = bl[j0 + jj];

    for (int k = 0; k < FEAT; k++) {
        float av = a_s[row * LDP + k];
        float xv = x_s[row * LDP + k];
        const float4* wl4 = (const float4*)(Wl + k * HDIM + j0);
        const float4* wr4 = (const float4*)(Wr + k * HDIM + j0);
#pragma unroll
        for (int q = 0; q < 8; q++) {
            float4 wl = wl4[q];
            float4 wr = wr4[q];
            h[4 * q + 0] += av * wl.x + xv * wr.x;
            h[4 * q + 1] += av * wl.y + xv * wr.y;
            h[4 * q + 2] += av * wl.z + xv * wr.z;
            h[4 * q + 3] += av * wl.w + xv * wr.w;
        }
    }

    // ---- head: per-thread partial t[16] over this thread's 32 j's ----
    float tp[16];
#pragma unroll
    for (int m = 0; m < 16; m++) tp[m] = 0.f;
#pragma unroll
    for (int jj = 0; jj < 32; jj++) {
        float hv = fmaxf(h[jj], 0.f);
        const float4* w14 = (const float4*)(W1 + (j0 + jj) * 16);
#pragma unroll
        for (int q = 0; q < 4; q++) {
            float4 w1 = w14[q];
            tp[4 * q + 0] += hv * w1.x;
            tp[4 * q + 1] += hv * w1.y;
            tp[4 * q + 2] += hv * w1.z;
            tp[4 * q + 3] += hv * w1.w;
        }
    }
    __syncthreads();  // done reading a_s/x_s; reuse smem for partials
    // layout: [row][jg*16 + m], row stride 65 -> (row + ...)%32 banks, 2-way
#pragma unroll
    for (int m = 0; m < 16; m++) smem[row * LDP + jg * 16 + m] = tp[m];
    __syncthreads();

    if (t < 64) {
        int rowg = row0 + t;
        if (rowg < N) {
            float o0 = b2[0], o1 = b2[1];
#pragma unroll
            for (int m = 0; m < 16; m++) {
                float tm = b1[m] + smem[t * LDP + m] + smem[t * LDP + 16 + m] +
                           smem[t * LDP + 32 + m] + smem[t * LDP + 48 + m];
                tm = fmaxf(tm, 0.f);
                o0 += tm * W2[m * 2 + 0];
                o1 += tm * W2[m * 2 + 1];
            }
            out[(size_t)rowg * 2 + 0] = o0;
            out[(size_t)rowg * 2 + 1] = o1;
        }
    }
}

extern "C" void kernel_launch(void* const* d_in, const int* in_sizes, int n_in,
                              void* d_out, int out_size, void* d_ws, size_t ws_size,
                              hipStream_t stream) {
    const float* x = (const float*)d_in[0];
    const int* ei = (const int*)d_in[1];
    // d_in[2] edge_weight, d_in[3] edge_features, d_in[4] adj, d_in[5] T: unused
    const float* gamma = (const float*)d_in[6];
    const float* beta = (const float*)d_in[7];
    const float* Wl = (const float*)d_in[8];
    const float* bl = (const float*)d_in[9];
    const float* Wr = (const float*)d_in[10];
    const float* W1 = (const float*)d_in[11];
    const float* b1 = (const float*)d_in[12];
    const float* W2 = (const float*)d_in[13];
    const float* b2 = (const float*)d_in[14];

    int N = in_sizes[0] / FEAT;
    int E = in_sizes[1] / 2;

    float* ws = (float*)d_ws;
    int degOff = 256;
    int xnOff = (256 + N + 3) & ~3;       // float4-aligned
    int aggOff = xnOff + N * FEAT;        // float4-aligned (N*64 % 4 == 0)

    float* out = (float*)d_out;

    hipLaunchKernelGGL(k0_zero, dim3(2048), dim3(256), 0, stream, ws, N, aggOff);
    hipLaunchKernelGGL(k1_stats, dim3(1024), dim3(256), 0, stream, x, ws, N);
    hipLaunchKernelGGL(k2_finalize, dim3(1), dim3(64), 0, stream, ws, gamma, beta, N);
    hipLaunchKernelGGL(k3_norm, dim3(2048), dim3(256), 0, stream, x, ws, ws + xnOff, N);

    int nscatter = E * FEAT;
    hipLaunchKernelGGL(k4_scatter, dim3((nscatter + 255) / 256), dim3(256), 0, stream,
                       ei, ws + xnOff, ws + aggOff, ws + degOff, E);

    hipLaunchKernelGGL(k5_gemm, dim3((N + ROWS - 1) / ROWS), dim3(256), 0, stream,
                       ws + aggOff, ws + xnOff, ws + degOff,
                       Wl, bl, Wr, W1, b1, W2, b2, out, N);
}

// Round 3
// 628.053 us; speedup vs baseline: 1.3382x; 1.1664x over previous
//
#include <hip/hip_runtime.h>

#define FEAT 64
#define HDIM 128
#define BN_EPS 1e-5f

// ws layout (float/int indices):
//   [0:256)    bn stats: colsum, colsumsq, scale, shift
//   [256]      global cursor (int)
//   [260:260+N)        count (int)
//   [260+N:260+2N)     rowStart (int)
//   [260+2N:260+3N)    cursor (int)
//   xnOff  = align4(260+3N)   : xn  (N*64 f32)
//   aggOff = xnOff + 64N      : agg (N*64 f32, pre-divided by deg)
//   srcOff = aggOff + 64N     : sortedSrc (E ints, pre-multiplied by 64)

// ---------------- K0: zero stats + gcur + count ----------------
__global__ void k0_zero(float* __restrict__ ws, int N) {
    int stride = gridDim.x * blockDim.x;
    int gid = blockIdx.x * blockDim.x + threadIdx.x;
    for (int i = gid; i < 260 + N; i += stride) ws[i] = 0.0f;
}

// ---------------- K1: column sums / sumsq ----------------
__global__ __launch_bounds__(256) void k1_stats(const float* __restrict__ x,
                                                float* __restrict__ ws, int N) {
    int col = threadIdx.x & 63;
    int rowInBlk = threadIdx.x >> 6;  // 0..3
    float s = 0.f, sq = 0.f;
    for (int r = blockIdx.x * 4 + rowInBlk; r < N; r += gridDim.x * 4) {
        float v = x[(size_t)r * FEAT + col];
        s += v;
        sq += v * v;
    }
    __shared__ float sd[256];
    __shared__ float sd2[256];
    sd[threadIdx.x] = s;
    sd2[threadIdx.x] = sq;
    __syncthreads();
    if (threadIdx.x < 64) {
        s = sd[col] + sd[col + 64] + sd[col + 128] + sd[col + 192];
        sq = sd2[col] + sd2[col + 64] + sd2[col + 128] + sd2[col + 192];
        atomicAdd(&ws[col], s);
        atomicAdd(&ws[64 + col], sq);
    }
}

// ---------------- K2: finalize scale/shift ----------------
__global__ void k2_finalize(float* __restrict__ ws, const float* __restrict__ gamma,
                            const float* __restrict__ beta, int N) {
    int c = threadIdx.x;  // 64 threads
    float invN = 1.0f / (float)N;
    float mean = ws[c] * invN;
    float var = ws[64 + c] * invN - mean * mean;
    float sc = rsqrtf(var + BN_EPS) * gamma[c];
    ws[128 + c] = sc;
    ws[192 + c] = beta[c] - mean * sc;
}

// ---------------- K3: xn = x*scale + shift ----------------
__global__ __launch_bounds__(256) void k3_norm(const float* __restrict__ x,
                                               const float* __restrict__ ws,
                                               float* __restrict__ xn, int N) {
    const float4* x4 = (const float4*)x;
    float4* o4 = (float4*)xn;
    int n4 = N * (FEAT / 4);
    int stride = gridDim.x * blockDim.x;
    for (int i = blockIdx.x * blockDim.x + threadIdx.x; i < n4; i += stride) {
        int cg = (i & 15) << 2;
        float4 v = x4[i];
        float4 sc = *(const float4*)(ws + 128 + cg);
        float4 sh = *(const float4*)(ws + 192 + cg);
        v.x = v.x * sc.x + sh.x;
        v.y = v.y * sc.y + sh.y;
        v.z = v.z * sc.z + sh.z;
        v.w = v.w * sc.w + sh.w;
        o4[i] = v;
    }
}

// ---------------- K4a: histogram of dst ----------------
__global__ __launch_bounds__(256) void k4a_hist(const int* __restrict__ ei,
                                                int* __restrict__ count, int E) {
    int e = blockIdx.x * 256 + threadIdx.x;
    if (e < E) atomicAdd(&count[ei[E + e]], 1);
}

// ---------------- K4b: allocate per-node regions ----------------
// block-local exclusive scan + one global-cursor atomic per block.
// Region order across blocks is arbitrary -- regions are disjoint, gather
// only needs (start, count) per node.
__global__ __launch_bounds__(256) void k4b_alloc(const int* __restrict__ count,
                                                 int* __restrict__ rowStart,
                                                 int* __restrict__ cursor,
                                                 int* __restrict__ gcur, int N) {
    __shared__ int sc[256];
    __shared__ int sbase;
    int i = blockIdx.x * 256 + threadIdx.x;
    int c = (i < N) ? count[i] : 0;
    sc[threadIdx.x] = c;
    __syncthreads();
    int v = c;
    for (int off = 1; off < 256; off <<= 1) {
        int add = (threadIdx.x >= (unsigned)off) ? sc[threadIdx.x - off] : 0;
        __syncthreads();
        v += add;
        sc[threadIdx.x] = v;
        __syncthreads();
    }
    if (threadIdx.x == 255) sbase = atomicAdd(gcur, v);
    __syncthreads();
    if (i < N) {
        int st = sbase + v - c;  // exclusive
        rowStart[i] = st;
        cursor[i] = st;
    }
}

// ---------------- K4c: fill bucketed src list ----------------
__global__ __launch_bounds__(256) void k4c_fill(const int* __restrict__ ei,
                                                int* __restrict__ cursor,
                                                int* __restrict__ sortedSrc, int E) {
    int e = blockIdx.x * 256 + threadIdx.x;
    if (e >= E) return;
    int src = ei[e];
    int dst = ei[E + e];
    int pos = atomicAdd(&cursor[dst], 1);
    sortedSrc[pos] = src * FEAT;  // pre-scaled row offset
}

// ---------------- K4d: gather + mean ----------------
// one wave per node; lane = feature. src offsets broadcast via shfl.
__global__ __launch_bounds__(256) void k4d_gather(const int* __restrict__ sortedSrc,
                                                  const int* __restrict__ rowStart,
                                                  const int* __restrict__ count,
                                                  const float* __restrict__ xn,
                                                  float* __restrict__ agg, int N) {
    int node = blockIdx.x * 4 + (threadIdx.x >> 6);
    if (node >= N) return;
    int lane = threadIdx.x & 63;
    int start = rowStart[node];
    int deg = count[node];
    float acc = 0.f;
    int e = 0;
    while (e < deg) {
        int chunk = min(64, deg - e);
        int myS = (lane < chunk) ? sortedSrc[start + e + lane] : 0;
        int j = 0;
        for (; j + 3 < chunk; j += 4) {
            int s0 = __shfl(myS, j + 0);
            int s1 = __shfl(myS, j + 1);
            int s2 = __shfl(myS, j + 2);
            int s3 = __shfl(myS, j + 3);
            float v0 = xn[s0 + lane];
            float v1 = xn[s1 + lane];
            float v2 = xn[s2 + lane];
            float v3 = xn[s3 + lane];
            acc += v0;
            acc += v1;
            acc += v2;
            acc += v3;
        }
        for (; j < chunk; j++) acc += xn[__shfl(myS, j) + lane];
        e += chunk;
    }
    float dinv = (deg > 0) ? (1.0f / (float)deg) : 0.0f;
    agg[(size_t)node * FEAT + lane] = acc * dinv;
}

// ---------------- K5: block-tiled fused GEMM + classifier head ----------------
#define ROWS 64
#define LDP 65  // padded LDS row stride

__global__ __launch_bounds__(256) void k5_gemm(const float* __restrict__ agg,
                                               const float* __restrict__ xn,
                                               const float* __restrict__ Wl,
                                               const float* __restrict__ bl,
                                               const float* __restrict__ Wr,
                                               const float* __restrict__ W1,
                                               const float* __restrict__ b1,
                                               const float* __restrict__ W2,
                                               const float* __restrict__ b2,
                                               float* __restrict__ out, int N) {
    __shared__ float smem[2 * ROWS * LDP];  // a_s, x_s; reused for t-partials
    float* a_s = smem;
    float* x_s = smem + ROWS * LDP;

    int row0 = blockIdx.x * ROWS;
    int t = threadIdx.x;

    for (int i = t; i < ROWS * 16; i += 256) {
        int r = i >> 4, cg = i & 15;
        int row = row0 + r;
        float4 av = make_float4(0.f, 0.f, 0.f, 0.f);
        float4 xv = av;
        if (row < N) {
            av = ((const float4*)(agg + (size_t)row * FEAT))[cg];
            xv = ((const float4*)(xn + (size_t)row * FEAT))[cg];
        }
        int base = r * LDP + cg * 4;
        a_s[base + 0] = av.x;
        a_s[base + 1] = av.y;
        a_s[base + 2] = av.z;
        a_s[base + 3] = av.w;
        x_s[base + 0] = xv.x;
        x_s[base + 1] = xv.y;
        x_s[base + 2] = xv.z;
        x_s[base + 3] = xv.w;
    }
    __syncthreads();

    int row = t & 63;
    int jg = t >> 6;  // wave-uniform
    int j0 = jg * 32;

    float h[32];
#pragma unroll
    for (int jj = 0; jj < 32; jj++) h[jj] = bl[j0 + jj];

    for (int k = 0; k < FEAT; k++) {
        float av = a_s[row * LDP + k];
        float xv = x_s[row * LDP + k];
        const float4* wl4 = (const float4*)(Wl + k * HDIM + j0);
        const float4* wr4 = (const float4*)(Wr + k * HDIM + j0);
#pragma unroll
        for (int q = 0; q < 8; q++) {
            float4 wl = wl4[q];
            float4 wr = wr4[q];
            h[4 * q + 0] += av * wl.x + xv * wr.x;
            h[4 * q + 1] += av * wl.y + xv * wr.y;
            h[4 * q + 2] += av * wl.z + xv * wr.z;
            h[4 * q + 3] += av * wl.w + xv * wr.w;
        }
    }

    float tp[16];
#pragma unroll
    for (int m = 0; m < 16; m++) tp[m] = 0.f;
#pragma unroll
    for (int jj = 0; jj < 32; jj++) {
        float hv = fmaxf(h[jj], 0.f);
        const float4* w14 = (const float4*)(W1 + (j0 + jj) * 16);
#pragma unroll
        for (int q = 0; q < 4; q++) {
            float4 w1 = w14[q];
            tp[4 * q + 0] += hv * w1.x;
            tp[4 * q + 1] += hv * w1.y;
            tp[4 * q + 2] += hv * w1.z;
            tp[4 * q + 3] += hv * w1.w;
        }
    }
    __syncthreads();
#pragma unroll
    for (int m = 0; m < 16; m++) smem[row * LDP + jg * 16 + m] = tp[m];
    __syncthreads();

    if (t < 64) {
        int rowg = row0 + t;
        if (rowg < N) {
            float o0 = b2[0], o1 = b2[1];
#pragma unroll
            for (int m = 0; m < 16; m++) {
                float tm = b1[m] + smem[t * LDP + m] + smem[t * LDP + 16 + m] +
                           smem[t * LDP + 32 + m] + smem[t * LDP + 48 + m];
                tm = fmaxf(tm, 0.f);
                o0 += tm * W2[m * 2 + 0];
                o1 += tm * W2[m * 2 + 1];
            }
            out[(size_t)rowg * 2 + 0] = o0;
            out[(size_t)rowg * 2 + 1] = o1;
        }
    }
}

extern "C" void kernel_launch(void* const* d_in, const int* in_sizes, int n_in,
                              void* d_out, int out_size, void* d_ws, size_t ws_size,
                              hipStream_t stream) {
    const float* x = (const float*)d_in[0];
    const int* ei = (const int*)d_in[1];
    const float* gamma = (const float*)d_in[6];
    const float* beta = (const float*)d_in[7];
    const float* Wl = (const float*)d_in[8];
    const float* bl = (const float*)d_in[9];
    const float* Wr = (const float*)d_in[10];
    const float* W1 = (const float*)d_in[11];
    const float* b1 = (const float*)d_in[12];
    const float* W2 = (const float*)d_in[13];
    const float* b2 = (const float*)d_in[14];

    int N = in_sizes[0] / FEAT;
    int E = in_sizes[1] / 2;

    float* ws = (float*)d_ws;
    int* wsi = (int*)d_ws;
    int gcurOff = 256;
    int countOff = 260;
    int rowStartOff = countOff + N;
    int cursorOff = rowStartOff + N;
    int xnOff = (cursorOff + N + 3) & ~3;
    int aggOff = xnOff + N * FEAT;
    int srcOff = aggOff + N * FEAT;

    float* out = (float*)d_out;

    hipLaunchKernelGGL(k0_zero, dim3(512), dim3(256), 0, stream, ws, N);
    hipLaunchKernelGGL(k1_stats, dim3(1024), dim3(256), 0, stream, x, ws, N);
    hipLaunchKernelGGL(k2_finalize, dim3(1), dim3(64), 0, stream, ws, gamma, beta, N);
    hipLaunchKernelGGL(k3_norm, dim3(2048), dim3(256), 0, stream, x, ws, ws + xnOff, N);

    int eb = (E + 255) / 256;
    hipLaunchKernelGGL(k4a_hist, dim3(eb), dim3(256), 0, stream, ei, wsi + countOff, E);
    hipLaunchKernelGGL(k4b_alloc, dim3((N + 255) / 256), dim3(256), 0, stream,
                       wsi + countOff, wsi + rowStartOff, wsi + cursorOff,
                       wsi + gcurOff, N);
    hipLaunchKernelGGL(k4c_fill, dim3(eb), dim3(256), 0, stream, ei, wsi + cursorOff,
                       wsi + srcOff, E);
    hipLaunchKernelGGL(k4d_gather, dim3((N + 3) / 4), dim3(256), 0, stream,
                       wsi + srcOff, wsi + rowStartOff, wsi + countOff,
                       ws + xnOff, ws + aggOff, N);

    hipLaunchKernelGGL(k5_gemm, dim3((N + ROWS - 1) / ROWS), dim3(256), 0, stream,
                       ws + aggOff, ws + xnOff,
                       Wl, bl, Wr, W1, b1, W2, b2, out, N);
}

// Round 4
// 418.521 us; speedup vs baseline: 2.0082x; 1.5006x over previous
//
#include <hip/hip_runtime.h>

#define FEAT 64
#define HDIM 128
#define BN_EPS 1e-5f

typedef __attribute__((ext_vector_type(8))) short bf16x8;
typedef __attribute__((ext_vector_type(4))) float f32x4;

__device__ inline unsigned short f2bf(float f) {
    union { float f; unsigned int u; } v;
    v.f = f;
    unsigned int r = (v.u + 0x7FFFu + ((v.u >> 16) & 1u)) >> 16;  // RNE
    return (unsigned short)r;
}
__device__ inline float bf2f(unsigned short b) {
    union { unsigned int u; float f; } v;
    v.u = ((unsigned int)b) << 16;
    return v.f;
}

// ws layout (float units):
//   [0:256)  bn stats: colsum, colsumsq, scale, shift
//   [256]    global cursor (int)
//   [260:260+N)     count (int)
//   [+N]            rowStart (int)
//   [+2N]           cursor (int)
//   wcOff  : Wc_t bf16 [128 n][128 k]  (16384 ushort = 8192 floats)
//   xnOff  : xn  bf16 [N][64]  (N*32 floats)
//   aggOff : agg bf16 [N][64]  (N*32 floats)
//   srcOff : sortedSrc (E ints, pre-multiplied by 64)

// ---------------- K0: zero stats + gcur + count ----------------
__global__ void k0_zero(float* __restrict__ ws, int N) {
    int stride = gridDim.x * blockDim.x;
    int gid = blockIdx.x * blockDim.x + threadIdx.x;
    for (int i = gid; i < 260 + N; i += stride) ws[i] = 0.0f;
}

// ---------------- K1: column sums / sumsq ----------------
__global__ __launch_bounds__(256) void k1_stats(const float* __restrict__ x,
                                                float* __restrict__ ws, int N) {
    int col = threadIdx.x & 63;
    int rowInBlk = threadIdx.x >> 6;
    float s = 0.f, sq = 0.f;
    for (int r = blockIdx.x * 4 + rowInBlk; r < N; r += gridDim.x * 4) {
        float v = x[(size_t)r * FEAT + col];
        s += v;
        sq += v * v;
    }
    __shared__ float sd[256];
    __shared__ float sd2[256];
    sd[threadIdx.x] = s;
    sd2[threadIdx.x] = sq;
    __syncthreads();
    if (threadIdx.x < 64) {
        s = sd[col] + sd[col + 64] + sd[col + 128] + sd[col + 192];
        sq = sd2[col] + sd2[col + 64] + sd2[col + 128] + sd2[col + 192];
        atomicAdd(&ws[col], s);
        atomicAdd(&ws[64 + col], sq);
    }
}

// ---------------- K2: finalize scale/shift ----------------
__global__ void k2_finalize(float* __restrict__ ws, const float* __restrict__ gamma,
                            const float* __restrict__ beta, int N) {
    int c = threadIdx.x;  // 64 threads
    float invN = 1.0f / (float)N;
    float mean = ws[c] * invN;
    float var = ws[64 + c] * invN - mean * mean;
    float sc = rsqrtf(var + BN_EPS) * gamma[c];
    ws[128 + c] = sc;
    ws[192 + c] = beta[c] - mean * sc;
}

// ---------------- K3: xn = bf16(x*scale + shift) ----------------
__global__ __launch_bounds__(256) void k3_norm(const float* __restrict__ x,
                                               const float* __restrict__ ws,
                                               unsigned short* __restrict__ xn, int N) {
    const float4* x4 = (const float4*)x;
    ushort4* o4 = (ushort4*)xn;
    int n4 = N * (FEAT / 4);
    int stride = gridDim.x * blockDim.x;
    for (int i = blockIdx.x * blockDim.x + threadIdx.x; i < n4; i += stride) {
        int cg = (i & 15) << 2;
        float4 v = x4[i];
        float4 sc = *(const float4*)(ws + 128 + cg);
        float4 sh = *(const float4*)(ws + 192 + cg);
        ushort4 o;
        o.x = f2bf(v.x * sc.x + sh.x);
        o.y = f2bf(v.y * sc.y + sh.y);
        o.z = f2bf(v.z * sc.z + sh.z);
        o.w = f2bf(v.w * sc.w + sh.w);
        o4[i] = o;
    }
}

// ---------------- KW: pack weights Wc_t[n][k] bf16 ----------------
__global__ __launch_bounds__(256) void kw_conv(const float* __restrict__ Wl,
                                               const float* __restrict__ Wr,
                                               unsigned short* __restrict__ Wc) {
    int id = blockIdx.x * 256 + threadIdx.x;  // 16384 total
    int n = id >> 7, k = id & 127;
    float w = (k < 64) ? Wl[k * HDIM + n] : Wr[(k - 64) * HDIM + n];
    Wc[n * 128 + k] = f2bf(w);
}

// ---------------- K4a: histogram of dst ----------------
__global__ __launch_bounds__(256) void k4a_hist(const int* __restrict__ ei,
                                                int* __restrict__ count, int E) {
    int e = blockIdx.x * 256 + threadIdx.x;
    if (e < E) atomicAdd(&count[ei[E + e]], 1);
}

// ---------------- K4b: allocate per-node regions ----------------
__global__ __launch_bounds__(256) void k4b_alloc(const int* __restrict__ count,
                                                 int* __restrict__ rowStart,
                                                 int* __restrict__ cursor,
                                                 int* __restrict__ gcur, int N) {
    __shared__ int sc[256];
    __shared__ int sbase;
    int i = blockIdx.x * 256 + threadIdx.x;
    int c = (i < N) ? count[i] : 0;
    sc[threadIdx.x] = c;
    __syncthreads();
    int v = c;
    for (int off = 1; off < 256; off <<= 1) {
        int add = (threadIdx.x >= (unsigned)off) ? sc[threadIdx.x - off] : 0;
        __syncthreads();
        v += add;
        sc[threadIdx.x] = v;
        __syncthreads();
    }
    if (threadIdx.x == 255) sbase = atomicAdd(gcur, v);
    __syncthreads();
    if (i < N) {
        int st = sbase + v - c;
        rowStart[i] = st;
        cursor[i] = st;
    }
}

// ---------------- K4c: fill bucketed src list ----------------
__global__ __launch_bounds__(256) void k4c_fill(const int* __restrict__ ei,
                                                int* __restrict__ cursor,
                                                int* __restrict__ sortedSrc, int E) {
    int e = blockIdx.x * 256 + threadIdx.x;
    if (e >= E) return;
    int src = ei[e];
    int dst = ei[E + e];
    int pos = atomicAdd(&cursor[dst], 1);
    sortedSrc[pos] = src * FEAT;  // pre-scaled row offset (ushort units)
}

// ---------------- K4d: gather + mean (bf16 xn -> bf16 agg) ----------------
__global__ __launch_bounds__(256) void k4d_gather(const int* __restrict__ sortedSrc,
                                                  const int* __restrict__ rowStart,
                                                  const int* __restrict__ count,
                                                  const unsigned short* __restrict__ xn,
                                                  unsigned short* __restrict__ agg,
                                                  int N) {
    int node = blockIdx.x * 4 + (threadIdx.x >> 6);
    if (node >= N) return;
    int lane = threadIdx.x & 63;
    int start = rowStart[node];
    int deg = count[node];
    float acc = 0.f;
    int e = 0;
    while (e < deg) {
        int chunk = min(64, deg - e);
        int myS = (lane < chunk) ? sortedSrc[start + e + lane] : 0;
        int j = 0;
        for (; j + 3 < chunk; j += 4) {
            int s0 = __shfl(myS, j + 0);
            int s1 = __shfl(myS, j + 1);
            int s2 = __shfl(myS, j + 2);
            int s3 = __shfl(myS, j + 3);
            float v0 = bf2f(xn[s0 + lane]);
            float v1 = bf2f(xn[s1 + lane]);
            float v2 = bf2f(xn[s2 + lane]);
            float v3 = bf2f(xn[s3 + lane]);
            acc += v0;
            acc += v1;
            acc += v2;
            acc += v3;
        }
        for (; j < chunk; j++) acc += bf2f(xn[__shfl(myS, j) + lane]);
        e += chunk;
    }
    float dinv = (deg > 0) ? (1.0f / (float)deg) : 0.0f;
    agg[(size_t)node * FEAT + lane] = f2bf(acc * dinv);
}

// ---------------- K5: MFMA GEMM (bf16) + fused head ----------------
// block = 4 waves = 64 rows x 128 cols, K=128. B frags in registers,
// A frags straight from global (read-once). Epilogue via LDS h_s.
#define HS 133  // h_s row stride (floats): 133*4B -> bank = 5*row+col, 2-way max

__global__ __launch_bounds__(256, 4) void k5_gemm(
    const unsigned short* __restrict__ agg, const unsigned short* __restrict__ xn,
    const unsigned short* __restrict__ Wc, const float* __restrict__ bl,
    const float* __restrict__ W1, const float* __restrict__ b1,
    const float* __restrict__ W2, const float* __restrict__ b2,
    float* __restrict__ out, int N) {
    __shared__ float h_s[64 * HS];  // ~34 KB
    int t = threadIdx.x;
    int lane = t & 63;
    int wv = t >> 6;   // wave id (wave-uniform)
    int rh = wv & 1;   // row half (32 rows)
    int ch = wv >> 1;  // col half (64 cols)
    int c = lane & 15;
    int q = lane >> 4;
    int row0 = blockIdx.x * 64;

    // B fragments: [nt][kt], n = lane&15, k = q*8+j  (m89-verified layout)
    bf16x8 bf[4][4];
#pragma unroll
    for (int nt = 0; nt < 4; nt++) {
        int col = ch * 64 + nt * 16 + c;
#pragma unroll
        for (int kt = 0; kt < 4; kt++)
            bf[nt][kt] = *(const bf16x8*)(Wc + col * 128 + kt * 32 + q * 8);
    }

    f32x4 acc[2][4];
    f32x4 z = {0.f, 0.f, 0.f, 0.f};
#pragma unroll
    for (int rt = 0; rt < 2; rt++)
#pragma unroll
        for (int nt = 0; nt < 4; nt++) acc[rt][nt] = z;

#pragma unroll
    for (int kt = 0; kt < 4; kt++) {
        const unsigned short* src = (kt < 2) ? agg : xn;  // k<64: agg, else xn
        int ko = (kt & 1) * 32 + q * 8;
        bf16x8 af[2];
#pragma unroll
        for (int rt = 0; rt < 2; rt++) {
            int row = row0 + rh * 32 + rt * 16 + c;
            row = min(row, N - 1);  // clamp; tail rows discarded at store
            af[rt] = *(const bf16x8*)(src + (size_t)row * FEAT + ko);
        }
#pragma unroll
        for (int rt = 0; rt < 2; rt++)
#pragma unroll
            for (int nt = 0; nt < 4; nt++)
                acc[rt][nt] = __builtin_amdgcn_mfma_f32_16x16x32_bf16(
                    af[rt], bf[nt][kt], acc[rt][nt], 0, 0, 0);
    }

    // epilogue: bias + relu -> h_s   (C layout: col=lane&15, row=q*4+reg)
#pragma unroll
    for (int rt = 0; rt < 2; rt++) {
        int rbase = rh * 32 + rt * 16 + q * 4;
#pragma unroll
        for (int nt = 0; nt < 4; nt++) {
            int col = ch * 64 + nt * 16 + c;
            float bias = bl[col];
#pragma unroll
            for (int r = 0; r < 4; r++)
                h_s[(rbase + r) * HS + col] = fmaxf(acc[rt][nt][r] + bias, 0.f);
        }
    }
    __syncthreads();

    // head: per-thread partial t[16] over 32 h-columns
    int row = t & 63;
    int jg = t >> 6;
    int j0 = jg * 32;
    float tp[16];
#pragma unroll
    for (int m = 0; m < 16; m++) tp[m] = 0.f;
    for (int jj = 0; jj < 32; jj++) {
        float hv = h_s[row * HS + j0 + jj];  // already relu'd
        const float4* w14 = (const float4*)(W1 + (j0 + jj) * 16);
#pragma unroll
        for (int qq = 0; qq < 4; qq++) {
            float4 w1 = w14[qq];
            tp[4 * qq + 0] += hv * w1.x;
            tp[4 * qq + 1] += hv * w1.y;
            tp[4 * qq + 2] += hv * w1.z;
            tp[4 * qq + 3] += hv * w1.w;
        }
    }
    __syncthreads();
#pragma unroll
    for (int m = 0; m < 16; m++) h_s[row * HS + jg * 16 + m] = tp[m];
    __syncthreads();

    if (t < 64) {
        int rowg = row0 + t;
        if (rowg < N) {
            float o0 = b2[0], o1 = b2[1];
#pragma unroll
            for (int m = 0; m < 16; m++) {
                float tm = b1[m] + h_s[t * HS + m] + h_s[t * HS + 16 + m] +
                           h_s[t * HS + 32 + m] + h_s[t * HS + 48 + m];
                tm = fmaxf(tm, 0.f);
                o0 += tm * W2[m * 2 + 0];
                o1 += tm * W2[m * 2 + 1];
            }
            out[(size_t)rowg * 2 + 0] = o0;
            out[(size_t)rowg * 2 + 1] = o1;
        }
    }
}

extern "C" void kernel_launch(void* const* d_in, const int* in_sizes, int n_in,
                              void* d_out, int out_size, void* d_ws, size_t ws_size,
                              hipStream_t stream) {
    const float* x = (const float*)d_in[0];
    const int* ei = (const int*)d_in[1];
    const float* gamma = (const float*)d_in[6];
    const float* beta = (const float*)d_in[7];
    const float* Wl = (const float*)d_in[8];
    const float* bl = (const float*)d_in[9];
    const float* Wr = (const float*)d_in[10];
    const float* W1 = (const float*)d_in[11];
    const float* b1 = (const float*)d_in[12];
    const float* W2 = (const float*)d_in[13];
    const float* b2 = (const float*)d_in[14];

    int N = in_sizes[0] / FEAT;
    int E = in_sizes[1] / 2;

    float* ws = (float*)d_ws;
    int* wsi = (int*)d_ws;
    int gcurOff = 256;
    int countOff = 260;
    int rowStartOff = countOff + N;
    int cursorOff = rowStartOff + N;
    int wcOff = (cursorOff + N + 3) & ~3;
    int xnOff = wcOff + 8192;           // Wc: 16384 ushorts
    int aggOff = xnOff + N * 32;        // xn: N*64 ushorts
    int srcOff = aggOff + N * 32;       // agg: N*64 ushorts

    unsigned short* xnp = (unsigned short*)(ws + xnOff);
    unsigned short* aggp = (unsigned short*)(ws + aggOff);
    unsigned short* wcp = (unsigned short*)(ws + wcOff);

    float* out = (float*)d_out;

    hipLaunchKernelGGL(k0_zero, dim3(512), dim3(256), 0, stream, ws, N);
    hipLaunchKernelGGL(k1_stats, dim3(1024), dim3(256), 0, stream, x, ws, N);
    hipLaunchKernelGGL(k2_finalize, dim3(1), dim3(64), 0, stream, ws, gamma, beta, N);
    hipLaunchKernelGGL(kw_conv, dim3(64), dim3(256), 0, stream, Wl, Wr, wcp);
    hipLaunchKernelGGL(k3_norm, dim3(2048), dim3(256), 0, stream, x, ws, xnp, N);

    int eb = (E + 255) / 256;
    hipLaunchKernelGGL(k4a_hist, dim3(eb), dim3(256), 0, stream, ei, wsi + countOff, E);
    hipLaunchKernelGGL(k4b_alloc, dim3((N + 255) / 256), dim3(256), 0, stream,
                       wsi + countOff, wsi + rowStartOff, wsi + cursorOff,
                       wsi + gcurOff, N);
    hipLaunchKernelGGL(k4c_fill, dim3(eb), dim3(256), 0, stream, ei, wsi + cursorOff,
                       wsi + srcOff, E);
    hipLaunchKernelGGL(k4d_gather, dim3((N + 3) / 4), dim3(256), 0, stream,
                       wsi + srcOff, wsi + rowStartOff, wsi + countOff,
                       xnp, aggp, N);

    hipLaunchKernelGGL(k5_gemm, dim3((N + 63) / 64), dim3(256), 0, stream,
                       aggp, xnp, wcp, bl, W1, b1, W2, b2, out, N);
}